// Round 8
// baseline (86.816 us; speedup 1.0000x reference)
//
#include <hip/hip_runtime.h>

#define H_DIM 2048
#define W_DIM 4096

typedef float fx4 __attribute__((ext_vector_type(4)));
typedef float f3v __attribute__((ext_vector_type(3)));

// ws layout (floats): [0]=final max; [64,64+32768)=k1 partials; then 1024 ring partials
#define WS_MAIN 64
#define WS_RING (64 + 32768)
#define RING_W  64

__device__ __forceinline__ void block_max_write(float m, float* __restrict__ dst) {
    #pragma unroll
    for (int off = 32; off > 0; off >>= 1)
        m = fmaxf(m, __shfl_down(m, off, 64));
    __shared__ float smax[4];
    if ((threadIdx.x & 63) == 0) smax[threadIdx.x >> 6] = m;
    __syncthreads();
    if (threadIdx.x == 0)
        *dst = fmaxf(fmaxf(smax[0], smax[1]), fmaxf(smax[2], smax[3]));
}

// exact per-pixel displacement (same arithmetic as reference path)
__device__ __forceinline__ void eval_disp(const float* __restrict__ disp,
                                          int iy, float fyc, int xx,
                                          float& dy, float& dx) {
    float ux = (float)xx * (2.0f / 4095.0f);
    int ix = min((int)ux, 1);
    float fxc = ux - (float)ix;
    const float* dp0 = disp + iy * 3 + ix;
    const float* dp1 = dp0 + 9;
    dy = 5.0f * ((1.0f - fyc) * ((1.0f - fxc) * dp0[0] + fxc * dp0[1])
               +          fyc  * ((1.0f - fxc) * dp0[3] + fxc * dp0[4]));
    dx = 5.0f * ((1.0f - fyc) * ((1.0f - fxc) * dp1[0] + fxc * dp1[1])
               +          fyc  * ((1.0f - fxc) * dp1[3] + fxc * dp1[4]));
}

// ---------------- ring max: 64-px frame (covers pixels no sample window loads) ----------------
#define RING_TOP_F4   (RING_W * 3072)                       // 196608
#define RING_SIDE_F4  ((H_DIM - 2 * RING_W) * 48)           // 92160
#define RING_TOT_F4   (2 * RING_TOP_F4 + 2 * RING_SIDE_F4)  // 577536

__global__ __launch_bounds__(256) void ring_max_kernel(const float* __restrict__ in,
                                                       float* __restrict__ wsf) {
    const fx4* __restrict__ in4 = (const fx4*)in;
    float m = 0.0f;
    for (int t = blockIdx.x * 256 + threadIdx.x; t < RING_TOT_F4; t += 1024 * 256) {
        int idx;
        if (t < RING_TOP_F4) {
            idx = t;                                                   // rows [0,64)
        } else if (t < 2 * RING_TOP_F4) {
            idx = (H_DIM - RING_W) * 3072 + (t - RING_TOP_F4);         // rows [1984,2048)
        } else if (t < 2 * RING_TOP_F4 + RING_SIDE_F4) {
            int u = t - 2 * RING_TOP_F4;                               // left cols [0,64)
            idx = (RING_W + u / 48) * 3072 + (u % 48);
        } else {
            int u = t - 2 * RING_TOP_F4 - RING_SIDE_F4;                // right cols [4032,4096)
            idx = (RING_W + u / 48) * 3072 + 3024 + (u % 48);
        }
        fx4 v = in4[idx];
        m = fmaxf(m, fmaxf(fmaxf(v.x, v.y), fmaxf(v.z, v.w)));
    }
    block_max_write(m, &wsf[WS_RING + blockIdx.x]);
}

// ---------------- k1: sample ALL blocks (OOB weights -> 0), emit per-block window max ----------------
__global__ __launch_bounds__(256) void elastic_main_kernel(const float* __restrict__ in,
                                                           const float* __restrict__ disp,
                                                           float* __restrict__ out,
                                                           float* __restrict__ wsf) {
    __shared__ __align__(16) float obuf[768];
    const int tid = threadIdx.x;
    int bid = blockIdx.x;
    int band = bid & 7;                  // XCD y-band swizzle
    int idx = bid >> 3;
    int y  = (band << 8) + (idx >> 4);
    int xs = (idx & 15) << 8;
    int x  = xs + tid;

    float uy = (float)y * (2.0f / 2047.0f);
    int iy = min((int)uy, 1);
    float fyc = uy - (float)iy;
    float dy, dx;
    eval_disp(disp, iy, fyc, x, dy, dx);

    float cy = (float)y + dy;
    float cx = (float)x + dx;
    float y0f = floorf(cy);
    float x0f = floorf(cx);
    float fy = cy - y0f;
    float fx = cx - x0f;
    int y0 = (int)y0f;
    int x0 = (int)x0f;

    int xbase = min(max(x0, 0), W_DIM - 2);
    bool sel = (x0 == xbase);
    bool vx0 = (x0 >= 0) & (x0 <= W_DIM - 1);
    bool vx1 = (x0 >= -1) & (x0 <= W_DIM - 2);
    int yr0 = min(max(y0, 0), H_DIM - 1);
    int yr1 = min(max(y0 + 1, 0), H_DIM - 1);
    bool vy0 = (y0 >= 0) & (y0 < H_DIM);
    bool vy1 = (y0 + 1 >= 0) & (y0 + 1 < H_DIM);

    const float* p0 = in + ((size_t)yr0 * W_DIM + xbase) * 3;
    const float* p1 = in + ((size_t)yr1 * W_DIM + xbase) * 3;

    f3v L00, L01, L10, L11;
    asm volatile("global_load_dwordx3 %0, %4, off\n\t"
                 "global_load_dwordx3 %1, %4, off offset:12\n\t"
                 "global_load_dwordx3 %2, %5, off\n\t"
                 "global_load_dwordx3 %3, %5, off offset:12"
                 : "=&v"(L00), "=&v"(L01), "=&v"(L10), "=&v"(L11)
                 : "v"(p0), "v"(p1));
    asm volatile("s_waitcnt vmcnt(0)"
                 : "+v"(L00), "+v"(L01), "+v"(L10), "+v"(L11));
    __builtin_amdgcn_sched_barrier(0);

    // per-thread max over raw loaded window (clamped loads are valid pixels)
    float mw = fmaxf(fmaxf(fmaxf(L00.x, L00.y), fmaxf(L00.z, L01.x)),
                     fmaxf(fmaxf(L01.y, L01.z), fmaxf(L10.x, L10.y)));
    mw = fmaxf(mw, fmaxf(fmaxf(L10.z, L11.x), fmaxf(L11.y, L11.z)));

    float g0 = 1.0f - fy, h0 = 1.0f - fx;
    float w00 = g0 * h0, w01 = g0 * fx, w10 = fy * h0, w11 = fy * fx;
    // zero weights for OOB corners (cval unknown here; border blocks get overwritten by k3)
    w00 = (vy0 & vx0) ? w00 : 0.0f;
    w01 = (vy0 & vx1) ? w01 : 0.0f;
    w10 = (vy1 & vx0) ? w10 : 0.0f;
    w11 = (vy1 & vx1) ? w11 : 0.0f;

    float c0a = sel ? L00.x : L01.x;  float c1a = sel ? L01.x : L00.x;
    float c0b = sel ? L00.y : L01.y;  float c1b = sel ? L01.y : L00.y;
    float c0c = sel ? L00.z : L01.z;  float c1c = sel ? L01.z : L00.z;
    float d0a = sel ? L10.x : L11.x;  float d1a = sel ? L11.x : L10.x;
    float d0b = sel ? L10.y : L11.y;  float d1b = sel ? L11.y : L10.y;
    float d0c = sel ? L10.z : L11.z;  float d1c = sel ? L11.z : L10.z;

    float acc0 = fmaf(w00, c0a, fmaf(w01, c1a, fmaf(w10, d0a, w11 * d1a)));
    float acc1 = fmaf(w00, c0b, fmaf(w01, c1b, fmaf(w10, d0b, w11 * d1b)));
    float acc2 = fmaf(w00, c0c, fmaf(w01, c1c, fmaf(w10, d0c, w11 * d1c)));

    obuf[tid * 3 + 0] = acc0;
    obuf[tid * 3 + 1] = acc1;
    obuf[tid * 3 + 2] = acc2;
    __syncthreads();
    if (tid < 192) {
        fx4 v = ((const fx4*)obuf)[tid];
        fx4* dst = ((fx4*)out) + ((size_t)y * W_DIM + xs) * 3 / 4 + tid;
        __builtin_nontemporal_store(v, dst);
    }
    block_max_write(mw, &wsf[WS_MAIN + blockIdx.x]);
}

// ---------------- k2: reduce 32768 + 1024 partials -> wsf[0] ----------------
__global__ __launch_bounds__(256) void max_final_kernel(float* __restrict__ wsf) {
    const fx4* pm = (const fx4*)(wsf + WS_MAIN);   // 8192 f4
    const fx4* pr = (const fx4*)(wsf + WS_RING);   // 256 f4
    float m = 0.0f;
    #pragma unroll
    for (int i = 0; i < 32; i++) {
        fx4 v = pm[threadIdx.x + i * 256];
        m = fmaxf(m, fmaxf(fmaxf(v.x, v.y), fmaxf(v.z, v.w)));
    }
    fx4 v = pr[threadIdx.x];
    m = fmaxf(m, fmaxf(fmaxf(v.x, v.y), fmaxf(v.z, v.w)));
    block_max_write(m, &wsf[0]);
}

// ---------------- k3: border blocks only — full cval path, overwrites k1 ----------------
__global__ __launch_bounds__(256) void elastic_border_kernel(const float* __restrict__ in,
                                                             const float* __restrict__ disp,
                                                             const float* __restrict__ wsf,
                                                             float* __restrict__ out) {
    const int tid = threadIdx.x;
    int bid = blockIdx.x;
    int y  = bid >> 4;
    int xs = (bid & 15) << 8;
    int x  = xs + tid;

    float uy = (float)y * (2.0f / 2047.0f);
    int iy = min((int)uy, 1);
    float fyc = uy - (float)iy;

    // block-uniform interior test (1px fp margin, conservative)
    float dyA, dxA, dyB, dxB;
    eval_disp(disp, iy, fyc, xs,       dyA, dxA);
    eval_disp(disp, iy, fyc, xs + 255, dyB, dxB);
    float cyLo = (float)y + fminf(dyA, dyB);
    float cyHi = (float)y + fmaxf(dyA, dyB);
    float cxLo = fminf((float)xs + dxA, (float)(xs + 255) + dxB);
    float cxHi = fmaxf((float)xs + dxA, (float)(xs + 255) + dxB);
    if (cyLo >= 1.0f && cyHi <= (float)(H_DIM - 3) &&
        cxLo >= 1.0f && cxHi <= (float)(W_DIM - 3))
        return;   // interior: k1's result is already complete

    const float cval = wsf[0];

    float dy, dx;
    eval_disp(disp, iy, fyc, x, dy, dx);
    float cy = (float)y + dy;
    float cx = (float)x + dx;
    float y0f = floorf(cy);
    float x0f = floorf(cx);
    float fy = cy - y0f;
    float fx = cx - x0f;
    int y0 = (int)y0f;
    int x0 = (int)x0f;

    int xbase = min(max(x0, 0), W_DIM - 2);
    bool sel = (x0 == xbase);
    bool vx0 = (x0 >= 0) & (x0 <= W_DIM - 1);
    bool vx1 = (x0 >= -1) & (x0 <= W_DIM - 2);
    int yr0 = min(max(y0, 0), H_DIM - 1);
    int yr1 = min(max(y0 + 1, 0), H_DIM - 1);
    bool vy0 = (y0 >= 0) & (y0 < H_DIM);
    bool vy1 = (y0 + 1 >= 0) & (y0 + 1 < H_DIM);

    const float* p0 = in + ((size_t)yr0 * W_DIM + xbase) * 3;
    const float* p1 = in + ((size_t)yr1 * W_DIM + xbase) * 3;
    f3v L00 = *(const f3v*)p0;
    f3v L01 = *(const f3v*)(p0 + 3);
    f3v L10 = *(const f3v*)p1;
    f3v L11 = *(const f3v*)(p1 + 3);

    float g0 = 1.0f - fy, h0 = 1.0f - fx;
    float w00 = g0 * h0, w01 = g0 * fx, w10 = fy * h0, w11 = fy * fx;

    float acc0, acc1, acc2;
    {
        float c0a = sel ? L00.x : L01.x;  float c1a = sel ? L01.x : L00.x;
        float c0b = sel ? L00.y : L01.y;  float c1b = sel ? L01.y : L00.y;
        float c0c = sel ? L00.z : L01.z;  float c1c = sel ? L01.z : L00.z;
        bool v0 = vy0 & vx0, v1 = vy0 & vx1;
        c0a = v0 ? c0a : cval;  c1a = v1 ? c1a : cval;
        c0b = v0 ? c0b : cval;  c1b = v1 ? c1b : cval;
        c0c = v0 ? c0c : cval;  c1c = v1 ? c1c : cval;
        acc0 = fmaf(w00, c0a, w01 * c1a);
        acc1 = fmaf(w00, c0b, w01 * c1b);
        acc2 = fmaf(w00, c0c, w01 * c1c);
    }
    {
        float c0a = sel ? L10.x : L11.x;  float c1a = sel ? L11.x : L10.x;
        float c0b = sel ? L10.y : L11.y;  float c1b = sel ? L11.y : L10.y;
        float c0c = sel ? L10.z : L11.z;  float c1c = sel ? L11.z : L10.z;
        bool v0 = vy1 & vx0, v1 = vy1 & vx1;
        c0a = v0 ? c0a : cval;  c1a = v1 ? c1a : cval;
        c0b = v0 ? c0b : cval;  c1b = v1 ? c1b : cval;
        c0c = v0 ? c0c : cval;  c1c = v1 ? c1c : cval;
        acc0 = fmaf(w10, c0a, fmaf(w11, c1a, acc0));
        acc1 = fmaf(w10, c0b, fmaf(w11, c1b, acc1));
        acc2 = fmaf(w10, c0c, fmaf(w11, c1c, acc2));
    }

    float* o = out + ((size_t)y * W_DIM + x) * 3;
    o[0] = acc0;
    o[1] = acc1;
    o[2] = acc2;
}

extern "C" void kernel_launch(void* const* d_in, const int* in_sizes, int n_in,
                              void* d_out, int out_size, void* d_ws, size_t ws_size,
                              hipStream_t stream) {
    const float* in   = (const float*)d_in[0];   // [2048, 4096, 3] f32
    const float* disp = (const float*)d_in[1];   // [2, 3, 3] f32
    float* out = (float*)d_out;
    float* wsf = (float*)d_ws;

    ring_max_kernel<<<1024, 256, 0, stream>>>(in, wsf);
    elastic_main_kernel<<<32768, 256, 0, stream>>>(in, disp, out, wsf);
    max_final_kernel<<<1, 256, 0, stream>>>(wsf);
    elastic_border_kernel<<<32768, 256, 0, stream>>>(in, disp, wsf, out);
}

// Round 9
// 56.243 us; speedup vs baseline: 1.5436x; 1.5436x over previous
//
#include <hip/hip_runtime.h>

#define H_DIM 2048
#define W_DIM 4096

typedef float fx4 __attribute__((ext_vector_type(4)));
typedef float f3v __attribute__((ext_vector_type(3)));

#define WS_PART_OFF 64
#define MAXP_BLOCKS 1024

// ---------------- Pass 1a: per-block partial max (no atomics); warms L3 ----------------
__global__ __launch_bounds__(256) void max_partial_kernel(const float* __restrict__ in,
                                                          float* __restrict__ wsf) {
    const float4* __restrict__ in4 = (const float4*)in;
    int t = blockIdx.x * 256 + threadIdx.x;
    float m = 0.0f;
    #pragma unroll
    for (int j = 0; j < 3; j++) {
        float4 v[8];
        #pragma unroll
        for (int k = 0; k < 8; k++) v[k] = in4[t + (j * 8 + k) * (MAXP_BLOCKS * 256)];
        #pragma unroll
        for (int k = 0; k < 8; k++)
            m = fmaxf(m, fmaxf(fmaxf(v[k].x, v[k].y), fmaxf(v[k].z, v[k].w)));
    }
    #pragma unroll
    for (int off = 32; off > 0; off >>= 1)
        m = fmaxf(m, __shfl_down(m, off, 64));
    __shared__ float smax[4];
    if ((threadIdx.x & 63) == 0) smax[threadIdx.x >> 6] = m;
    __syncthreads();
    if (threadIdx.x == 0)
        wsf[WS_PART_OFF + blockIdx.x] = fmaxf(fmaxf(smax[0], smax[1]), fmaxf(smax[2], smax[3]));
}

// ---------------- Pass 1b: reduce 1024 partials -> wsf[0] ----------------
__global__ __launch_bounds__(256) void max_final_kernel(float* __restrict__ wsf) {
    const float4* p4 = (const float4*)(wsf + WS_PART_OFF);
    float4 v = p4[threadIdx.x];
    float m = fmaxf(fmaxf(v.x, v.y), fmaxf(v.z, v.w));
    #pragma unroll
    for (int off = 32; off > 0; off >>= 1)
        m = fmaxf(m, __shfl_down(m, off, 64));
    __shared__ float smax[4];
    if ((threadIdx.x & 63) == 0) smax[threadIdx.x >> 6] = m;
    __syncthreads();
    if (threadIdx.x == 0)
        wsf[0] = fmaxf(fmaxf(smax[0], smax[1]), fmaxf(smax[2], smax[3]));
}

__device__ __forceinline__ void eval_disp(const float* __restrict__ disp,
                                          int iy, float fyc, int xx,
                                          float& dy, float& dx) {
    float ux = (float)xx * (2.0f / 4095.0f);
    int ix = min((int)ux, 1);
    float fxc = ux - (float)ix;
    const float* dp0 = disp + iy * 3 + ix;
    const float* dp1 = dp0 + 9;
    dy = 5.0f * ((1.0f - fyc) * ((1.0f - fxc) * dp0[0] + fxc * dp0[1])
               +          fyc  * ((1.0f - fxc) * dp0[3] + fxc * dp0[4]));
    dx = 5.0f * ((1.0f - fyc) * ((1.0f - fxc) * dp1[0] + fxc * dp1[1])
               +          fyc  * ((1.0f - fxc) * dp1[3] + fxc * dp1[4]));
}

// ---------------- Pass 2: elastic warp, block-uniform interior fast path ----------------
__global__ __launch_bounds__(256) void elastic_sample_kernel(const float* __restrict__ in,
                                                             const float* __restrict__ disp,
                                                             const float* __restrict__ wsf,
                                                             float* __restrict__ out) {
    const int tid = threadIdx.x;
    int bid = blockIdx.x;
    int band = bid & 7;                  // XCD y-band swizzle
    int idx = bid >> 3;
    int y  = (band << 8) + (idx >> 4);
    int xs = (idx & 15) << 8;
    int x  = xs + tid;

    float uy = (float)y * (2.0f / 2047.0f);
    int iy = min((int)uy, 1);
    float fyc = uy - (float)iy;

    // block-uniform endpoint bounds (disp linear in x within the block; cell-aligned)
    float dyA, dxA, dyB, dxB;
    eval_disp(disp, iy, fyc, xs,       dyA, dxA);
    eval_disp(disp, iy, fyc, xs + 255, dyB, dxB);
    float cyLo = (float)y + fminf(dyA, dyB);
    float cyHi = (float)y + fmaxf(dyA, dyB);
    float cxLo = fminf((float)xs + dxA, (float)(xs + 255) + dxB);
    float cxHi = fmaxf((float)xs + dxA, (float)(xs + 255) + dxB);
    bool interior = (cyLo >= 1.0f) & (cyHi <= (float)(H_DIM - 3)) &&
                    (cxLo >= 1.0f) & (cxHi <= (float)(W_DIM - 3));

    float acc0, acc1, acc2;

    if (interior) {
        // ---- fast path: linear disp, no clamps/masks/selects, no LDS/barriers ----
        float sY = (dyB - dyA) * (1.0f / 255.0f);
        float sX = (dxB - dxA) * (1.0f / 255.0f);
        float cy = (float)y + fmaf((float)tid, sY, dyA);
        float cx = (float)x + fmaf((float)tid, sX, dxA);
        float y0f = floorf(cy);
        float x0f = floorf(cx);
        float fy = cy - y0f;
        float fx = cx - x0f;
        int y0 = (int)y0f;
        int x0 = (int)x0f;

        const float* p0 = in + ((size_t)y0 * W_DIM + x0) * 3;
        const float* p1 = p0 + W_DIM * 3;

        f3v L00, L01, L10, L11;
        asm volatile("global_load_dwordx3 %0, %4, off\n\t"
                     "global_load_dwordx3 %1, %4, off offset:12\n\t"
                     "global_load_dwordx3 %2, %5, off\n\t"
                     "global_load_dwordx3 %3, %5, off offset:12"
                     : "=&v"(L00), "=&v"(L01), "=&v"(L10), "=&v"(L11)
                     : "v"(p0), "v"(p1));
        asm volatile("s_waitcnt vmcnt(0)"
                     : "+v"(L00), "+v"(L01), "+v"(L10), "+v"(L11));
        __builtin_amdgcn_sched_barrier(0);

        float g0 = 1.0f - fy, h0 = 1.0f - fx;
        float w00 = g0 * h0, w01 = g0 * fx, w10 = fy * h0, w11 = fy * fx;
        acc0 = fmaf(w00, L00.x, fmaf(w01, L01.x, fmaf(w10, L10.x, w11 * L11.x)));
        acc1 = fmaf(w00, L00.y, fmaf(w01, L01.y, fmaf(w10, L10.y, w11 * L11.y)));
        acc2 = fmaf(w00, L00.z, fmaf(w01, L01.z, fmaf(w10, L10.z, w11 * L11.z)));
    } else {
        // ---- slow path: exact per-pixel disp, clamps + cval masks ----
        const float cval = wsf[0];
        float dy, dx;
        eval_disp(disp, iy, fyc, x, dy, dx);
        float cy = (float)y + dy;
        float cx = (float)x + dx;
        float y0f = floorf(cy);
        float x0f = floorf(cx);
        float fy = cy - y0f;
        float fx = cx - x0f;
        int y0 = (int)y0f;
        int x0 = (int)x0f;

        int xbase = min(max(x0, 0), W_DIM - 2);
        bool sel = (x0 == xbase);
        bool vx0 = (x0 >= 0) & (x0 <= W_DIM - 1);
        bool vx1 = (x0 >= -1) & (x0 <= W_DIM - 2);
        int yr0 = min(max(y0, 0), H_DIM - 1);
        int yr1 = min(max(y0 + 1, 0), H_DIM - 1);
        bool vy0 = (y0 >= 0) & (y0 < H_DIM);
        bool vy1 = (y0 + 1 >= 0) & (y0 + 1 < H_DIM);

        const float* p0 = in + ((size_t)yr0 * W_DIM + xbase) * 3;
        const float* p1 = in + ((size_t)yr1 * W_DIM + xbase) * 3;
        f3v L00 = *(const f3v*)p0;
        f3v L01 = *(const f3v*)(p0 + 3);
        f3v L10 = *(const f3v*)p1;
        f3v L11 = *(const f3v*)(p1 + 3);

        float g0 = 1.0f - fy, h0 = 1.0f - fx;
        float w00 = g0 * h0, w01 = g0 * fx, w10 = fy * h0, w11 = fy * fx;
        {
            float c0a = sel ? L00.x : L01.x;  float c1a = sel ? L01.x : L00.x;
            float c0b = sel ? L00.y : L01.y;  float c1b = sel ? L01.y : L00.y;
            float c0c = sel ? L00.z : L01.z;  float c1c = sel ? L01.z : L00.z;
            bool v0 = vy0 & vx0, v1 = vy0 & vx1;
            c0a = v0 ? c0a : cval;  c1a = v1 ? c1a : cval;
            c0b = v0 ? c0b : cval;  c1b = v1 ? c1b : cval;
            c0c = v0 ? c0c : cval;  c1c = v1 ? c1c : cval;
            acc0 = fmaf(w00, c0a, w01 * c1a);
            acc1 = fmaf(w00, c0b, w01 * c1b);
            acc2 = fmaf(w00, c0c, w01 * c1c);
        }
        {
            float c0a = sel ? L10.x : L11.x;  float c1a = sel ? L11.x : L10.x;
            float c0b = sel ? L10.y : L11.y;  float c1b = sel ? L11.y : L10.y;
            float c0c = sel ? L10.z : L11.z;  float c1c = sel ? L11.z : L10.z;
            bool v0 = vy1 & vx0, v1 = vy1 & vx1;
            c0a = v0 ? c0a : cval;  c1a = v1 ? c1a : cval;
            c0b = v0 ? c0b : cval;  c1b = v1 ? c1b : cval;
            c0c = v0 ? c0c : cval;  c1c = v1 ? c1c : cval;
            acc0 = fmaf(w10, c0a, fmaf(w11, c1a, acc0));
            acc1 = fmaf(w10, c0b, fmaf(w11, c1b, acc1));
            acc2 = fmaf(w10, c0c, fmaf(w11, c1c, acc2));
        }
    }

    // direct 12B store (64 lanes contiguous -> 12 lines/wave, one instr)
    f3v r;
    r.x = acc0; r.y = acc1; r.z = acc2;
    float* o = out + ((size_t)y * W_DIM + x) * 3;
    asm volatile("global_store_dwordx3 %0, %1, off" :: "v"(o), "v"(r) : "memory");
}

extern "C" void kernel_launch(void* const* d_in, const int* in_sizes, int n_in,
                              void* d_out, int out_size, void* d_ws, size_t ws_size,
                              hipStream_t stream) {
    const float* in   = (const float*)d_in[0];   // [2048, 4096, 3] f32
    const float* disp = (const float*)d_in[1];   // [2, 3, 3] f32
    float* out = (float*)d_out;
    float* wsf = (float*)d_ws;

    max_partial_kernel<<<MAXP_BLOCKS, 256, 0, stream>>>(in, wsf);
    max_final_kernel<<<1, 256, 0, stream>>>(wsf);
    elastic_sample_kernel<<<32768, 256, 0, stream>>>(in, disp, wsf, out);
}

// Round 10
// 54.008 us; speedup vs baseline: 1.6075x; 1.0414x over previous
//
#include <hip/hip_runtime.h>

#define H_DIM 2048
#define W_DIM 4096

typedef float fx4 __attribute__((ext_vector_type(4)));
typedef float f3v __attribute__((ext_vector_type(3)));

#define WS_PART_OFF 64
#define MAXP_BLOCKS 2048

// ---------------- Pass 1a: per-block partial max (no atomics); warms L3 ----------------
// 2048 blocks x 256 thr = 524288 threads; 6291456 float4 = 12/thread, all 12 in flight.
__global__ __launch_bounds__(256) void max_partial_kernel(const float* __restrict__ in,
                                                          float* __restrict__ wsf) {
    const float4* __restrict__ in4 = (const float4*)in;
    int t = blockIdx.x * 256 + threadIdx.x;
    float4 v[12];
    #pragma unroll
    for (int k = 0; k < 12; k++) v[k] = in4[t + k * (MAXP_BLOCKS * 256)];
    float m = 0.0f;
    #pragma unroll
    for (int k = 0; k < 12; k++)
        m = fmaxf(m, fmaxf(fmaxf(v[k].x, v[k].y), fmaxf(v[k].z, v[k].w)));
    #pragma unroll
    for (int off = 32; off > 0; off >>= 1)
        m = fmaxf(m, __shfl_down(m, off, 64));
    __shared__ float smax[4];
    if ((threadIdx.x & 63) == 0) smax[threadIdx.x >> 6] = m;
    __syncthreads();
    if (threadIdx.x == 0)
        wsf[WS_PART_OFF + blockIdx.x] = fmaxf(fmaxf(smax[0], smax[1]), fmaxf(smax[2], smax[3]));
}

// ---------------- Pass 1b: reduce 2048 partials -> wsf[0] ----------------
__global__ __launch_bounds__(256) void max_final_kernel(float* __restrict__ wsf) {
    const float4* p4 = (const float4*)(wsf + WS_PART_OFF);
    float4 a = p4[threadIdx.x];
    float4 b = p4[threadIdx.x + 256];
    float m = fmaxf(fmaxf(fmaxf(a.x, a.y), fmaxf(a.z, a.w)),
                    fmaxf(fmaxf(b.x, b.y), fmaxf(b.z, b.w)));
    #pragma unroll
    for (int off = 32; off > 0; off >>= 1)
        m = fmaxf(m, __shfl_down(m, off, 64));
    __shared__ float smax[4];
    if ((threadIdx.x & 63) == 0) smax[threadIdx.x >> 6] = m;
    __syncthreads();
    if (threadIdx.x == 0)
        wsf[0] = fmaxf(fmaxf(smax[0], smax[1]), fmaxf(smax[2], smax[3]));
}

__device__ __forceinline__ void eval_disp(const float* __restrict__ disp,
                                          int iy, float fyc, int xx,
                                          float& dy, float& dx) {
    float ux = (float)xx * (2.0f / 4095.0f);
    int ix = min((int)ux, 1);
    float fxc = ux - (float)ix;
    const float* dp0 = disp + iy * 3 + ix;
    const float* dp1 = dp0 + 9;
    dy = 5.0f * ((1.0f - fyc) * ((1.0f - fxc) * dp0[0] + fxc * dp0[1])
               +          fyc  * ((1.0f - fxc) * dp0[3] + fxc * dp0[4]));
    dx = 5.0f * ((1.0f - fyc) * ((1.0f - fxc) * dp1[0] + fxc * dp1[1])
               +          fyc  * ((1.0f - fxc) * dp1[3] + fxc * dp1[4]));
}

// ---------------- Pass 2: elastic warp, interior fast path, NT output stores ----------------
__global__ __launch_bounds__(256) void elastic_sample_kernel(const float* __restrict__ in,
                                                             const float* __restrict__ disp,
                                                             const float* __restrict__ wsf,
                                                             float* __restrict__ out) {
    const int tid = threadIdx.x;
    int bid = blockIdx.x;
    int band = bid & 7;                  // XCD y-band swizzle
    int idx = bid >> 3;
    int y  = (band << 8) + (idx >> 4);
    int xs = (idx & 15) << 8;
    int x  = xs + tid;

    float uy = (float)y * (2.0f / 2047.0f);
    int iy = min((int)uy, 1);
    float fyc = uy - (float)iy;

    // block-uniform endpoint bounds (disp linear in x within the block; cell-aligned)
    float dyA, dxA, dyB, dxB;
    eval_disp(disp, iy, fyc, xs,       dyA, dxA);
    eval_disp(disp, iy, fyc, xs + 255, dyB, dxB);
    float cyLo = (float)y + fminf(dyA, dyB);
    float cyHi = (float)y + fmaxf(dyA, dyB);
    float cxLo = fminf((float)xs + dxA, (float)(xs + 255) + dxB);
    float cxHi = fmaxf((float)xs + dxA, (float)(xs + 255) + dxB);
    bool interior = (cyLo >= 1.0f) & (cyHi <= (float)(H_DIM - 3)) &&
                    (cxLo >= 1.0f) & (cxHi <= (float)(W_DIM - 3));

    float acc0, acc1, acc2;

    if (interior) {
        // ---- fast path: linear disp, no clamps/masks/selects, no LDS/barriers ----
        float sY = (dyB - dyA) * (1.0f / 255.0f);
        float sX = (dxB - dxA) * (1.0f / 255.0f);
        float cy = (float)y + fmaf((float)tid, sY, dyA);
        float cx = (float)x + fmaf((float)tid, sX, dxA);
        float y0f = floorf(cy);
        float x0f = floorf(cx);
        float fy = cy - y0f;
        float fx = cx - x0f;
        int y0 = (int)y0f;
        int x0 = (int)x0f;

        const float* p0 = in + ((size_t)y0 * W_DIM + x0) * 3;
        const float* p1 = p0 + W_DIM * 3;

        f3v L00, L01, L10, L11;
        asm volatile("global_load_dwordx3 %0, %4, off\n\t"
                     "global_load_dwordx3 %1, %4, off offset:12\n\t"
                     "global_load_dwordx3 %2, %5, off\n\t"
                     "global_load_dwordx3 %3, %5, off offset:12"
                     : "=&v"(L00), "=&v"(L01), "=&v"(L10), "=&v"(L11)
                     : "v"(p0), "v"(p1));
        asm volatile("s_waitcnt vmcnt(0)"
                     : "+v"(L00), "+v"(L01), "+v"(L10), "+v"(L11));
        __builtin_amdgcn_sched_barrier(0);

        float g0 = 1.0f - fy, h0 = 1.0f - fx;
        float w00 = g0 * h0, w01 = g0 * fx, w10 = fy * h0, w11 = fy * fx;
        acc0 = fmaf(w00, L00.x, fmaf(w01, L01.x, fmaf(w10, L10.x, w11 * L11.x)));
        acc1 = fmaf(w00, L00.y, fmaf(w01, L01.y, fmaf(w10, L10.y, w11 * L11.y)));
        acc2 = fmaf(w00, L00.z, fmaf(w01, L01.z, fmaf(w10, L10.z, w11 * L11.z)));
    } else {
        // ---- slow path: exact per-pixel disp, clamps + cval masks ----
        const float cval = wsf[0];
        float dy, dx;
        eval_disp(disp, iy, fyc, x, dy, dx);
        float cy = (float)y + dy;
        float cx = (float)x + dx;
        float y0f = floorf(cy);
        float x0f = floorf(cx);
        float fy = cy - y0f;
        float fx = cx - x0f;
        int y0 = (int)y0f;
        int x0 = (int)x0f;

        int xbase = min(max(x0, 0), W_DIM - 2);
        bool sel = (x0 == xbase);
        bool vx0 = (x0 >= 0) & (x0 <= W_DIM - 1);
        bool vx1 = (x0 >= -1) & (x0 <= W_DIM - 2);
        int yr0 = min(max(y0, 0), H_DIM - 1);
        int yr1 = min(max(y0 + 1, 0), H_DIM - 1);
        bool vy0 = (y0 >= 0) & (y0 < H_DIM);
        bool vy1 = (y0 + 1 >= 0) & (y0 + 1 < H_DIM);

        const float* p0 = in + ((size_t)yr0 * W_DIM + xbase) * 3;
        const float* p1 = in + ((size_t)yr1 * W_DIM + xbase) * 3;
        f3v L00 = *(const f3v*)p0;
        f3v L01 = *(const f3v*)(p0 + 3);
        f3v L10 = *(const f3v*)p1;
        f3v L11 = *(const f3v*)(p1 + 3);

        float g0 = 1.0f - fy, h0 = 1.0f - fx;
        float w00 = g0 * h0, w01 = g0 * fx, w10 = fy * h0, w11 = fy * fx;
        {
            float c0a = sel ? L00.x : L01.x;  float c1a = sel ? L01.x : L00.x;
            float c0b = sel ? L00.y : L01.y;  float c1b = sel ? L01.y : L00.y;
            float c0c = sel ? L00.z : L01.z;  float c1c = sel ? L01.z : L00.z;
            bool v0 = vy0 & vx0, v1 = vy0 & vx1;
            c0a = v0 ? c0a : cval;  c1a = v1 ? c1a : cval;
            c0b = v0 ? c0b : cval;  c1b = v1 ? c1b : cval;
            c0c = v0 ? c0c : cval;  c1c = v1 ? c1c : cval;
            acc0 = fmaf(w00, c0a, w01 * c1a);
            acc1 = fmaf(w00, c0b, w01 * c1b);
            acc2 = fmaf(w00, c0c, w01 * c1c);
        }
        {
            float c0a = sel ? L10.x : L11.x;  float c1a = sel ? L11.x : L10.x;
            float c0b = sel ? L10.y : L11.y;  float c1b = sel ? L11.y : L10.y;
            float c0c = sel ? L10.z : L11.z;  float c1c = sel ? L11.z : L10.z;
            bool v0 = vy1 & vx0, v1 = vy1 & vx1;
            c0a = v0 ? c0a : cval;  c1a = v1 ? c1a : cval;
            c0b = v0 ? c0b : cval;  c1b = v1 ? c1b : cval;
            c0c = v0 ? c0c : cval;  c1c = v1 ? c1c : cval;
            acc0 = fmaf(w10, c0a, fmaf(w11, c1a, acc0));
            acc1 = fmaf(w10, c0b, fmaf(w11, c1b, acc1));
            acc2 = fmaf(w10, c0c, fmaf(w11, c1c, acc2));
        }
    }

    // non-temporal 12B store: stream the output past L3 so the warm input stays resident
    f3v r;
    r.x = acc0; r.y = acc1; r.z = acc2;
    f3v* o = (f3v*)(out + ((size_t)y * W_DIM + x) * 3);
    __builtin_nontemporal_store(r, o);
}

extern "C" void kernel_launch(void* const* d_in, const int* in_sizes, int n_in,
                              void* d_out, int out_size, void* d_ws, size_t ws_size,
                              hipStream_t stream) {
    const float* in   = (const float*)d_in[0];   // [2048, 4096, 3] f32
    const float* disp = (const float*)d_in[1];   // [2, 3, 3] f32
    float* out = (float*)d_out;
    float* wsf = (float*)d_ws;

    max_partial_kernel<<<MAXP_BLOCKS, 256, 0, stream>>>(in, wsf);
    max_final_kernel<<<1, 256, 0, stream>>>(wsf);
    elastic_sample_kernel<<<32768, 256, 0, stream>>>(in, disp, wsf, out);
}